// Round 3
// baseline (91.194 us; speedup 1.0000x reference)
//
#include <hip/hip_runtime.h>

#define NN 8192

typedef float f32x4 __attribute__((ext_vector_type(4)));

// ---------------- Kernel A: LIF fire (tiny, N elements) ----------------
__global__ void lif_fire_kernel(const int* __restrict__ in_spk,
                                const float* __restrict__ mp,
                                const float* __restrict__ rp,
                                float* __restrict__ out_spikes,
                                float* __restrict__ out_v,
                                float* __restrict__ out_r) {
    int i = blockIdx.x * blockDim.x + threadIdx.x;
    if (i >= NN) return;
    float v = mp[i] + (float)in_spk[i] * 1.0f;           // input_signal = spikes * THRESHOLD
    float r = fmaxf(rp[i] - 1.0f, 0.0f);
    bool spike = (v >= 1.0f) && (r == 0.0f);
    float s = spike ? 1.0f : 0.0f;
    v = spike ? 0.0f : v;
    r = r + s * 5.0f;                                    // TAU_REFRACT
    out_spikes[i] = s;
    out_v[i] = v;
    out_r[i] = r;
}

// ---------------- Kernel B: STDP weight update (N*N streaming) ----------------
// Memory-bound: 256 MiB read + 256 MiB write of weights. Roofline ~85 us
// at 6.3 TB/s achievable HBM. Per-element ALU (few VALU + rare v_exp_f32)
// is far below the memory time.
__global__ __launch_bounds__(256)
void stdp_update_kernel(const float* __restrict__ w_in,
                        const float* __restrict__ spikes,
                        float* __restrict__ w_out) {
    const size_t n4 = (size_t)NN * (NN / 4);        // 16,777,216 float4s
    const f32x4* __restrict__ win4 = (const f32x4*)w_in;
    f32x4* __restrict__ wout4 = (f32x4*)w_out;
    const f32x4* __restrict__ spk4 = (const f32x4*)spikes;
    const float ninv = -1.0f / 800.0f;              // -1/(2*TAU_PLUS^2)

    size_t stride = (size_t)gridDim.x * blockDim.x;
    for (size_t idx = (size_t)blockIdx.x * blockDim.x + threadIdx.x;
         idx < n4; idx += stride) {
        int row = (int)(idx >> 11);                 // idx / 2048 (2048 float4/row)
        int c4  = (int)(idx & 2047);
        int j0  = c4 << 2;
        f32x4 w = win4[idx];
        float si = spikes[row];                     // wave-uniform (64 lanes share a row)
        if (si != 0.0f) {
            // pre-neuron spiked: LTP term for each of the 4 columns
            f32x4 sj = spk4[c4];
            int d0 = j0 - row;
            #pragma unroll
            for (int k = 0; k < 4; ++k) {
                int dti = d0 + k;
                float sjk = sj[k];
                if (dti > 0 && sjk != 0.0f) {
                    float dt = (float)dti;
                    w[k] += 0.01f * __expf(dt * dt * ninv);
                }
            }
        }
        // clip(.., 0, 1) applies to the FULL matrix (masked or not)
        #pragma unroll
        for (int k = 0; k < 4; ++k)
            w[k] = fminf(fmaxf(w[k], 0.0f), 1.0f);
        __builtin_nontemporal_store(w, &wout4[idx]);
    }
}

extern "C" void kernel_launch(void* const* d_in, const int* in_sizes, int n_in,
                              void* d_out, int out_size, void* d_ws, size_t ws_size,
                              hipStream_t stream) {
    const int*   in_spk = (const int*)d_in[0];     // input_spikes  int32 [N]
    const float* w_in   = (const float*)d_in[1];   // weights       f32   [N*N]
    const float* mp     = (const float*)d_in[2];   // membrane_potential  [N]
    const float* rp     = (const float*)d_in[3];   // refractory_period   [N]

    float* out = (float*)d_out;
    // return order: spikes[N], new_weights[N*N], v[N], r[N]
    float* out_spikes = out;
    float* out_w      = out + NN;
    float* out_v      = out + NN + (size_t)NN * NN;
    float* out_r      = out_v + NN;

    // Kernel A: compute spikes/v/r
    lif_fire_kernel<<<(NN + 255) / 256, 256, 0, stream>>>(
        in_spk, mp, rp, out_spikes, out_v, out_r);

    // Kernel B: streaming weight update, grid-stride
    const int blocks = 2048;                       // ~8 blocks/CU, grid-stride rest
    stdp_update_kernel<<<blocks, 256, 0, stream>>>(w_in, out_spikes, out_w);
}